// Round 3
// baseline (700.340 us; speedup 1.0000x reference)
//
#include <hip/hip_runtime.h>
#include <hip/hip_bf16.h>

// VisionEncoderLayer: B=16 S=1024 H=768 NH=12 HD=64 I=3072, fp32 in/out.
// Strategy: bf16 MFMA (16x16x32) GEMMs + flash attention, fp32 accum/residual/LN.

#define H_ 768
#define I_ 3072
#define NTOK 16384   // 16*1024
#define SEQ 1024
#define NH_ 12

typedef __attribute__((ext_vector_type(8))) __bf16 bf16x8;
typedef __attribute__((ext_vector_type(4))) __bf16 bf16x4;
typedef __attribute__((ext_vector_type(4))) float  f32x4;

__device__ __forceinline__ void gll16(const void* g, void* l) {
  // async global->LDS, 16B per lane; LDS dest = wave-uniform base + lane*16
  __builtin_amdgcn_global_load_lds(
      (const __attribute__((address_space(1))) unsigned int*)g,
      (__attribute__((address_space(3))) unsigned int*)l, 16, 0, 0);
}

// ---------------- fp32 -> bf16 convert ----------------
__global__ __launch_bounds__(256) void f2b(const float* __restrict__ s,
                                           __bf16* __restrict__ d, int n) {
  int i = (blockIdx.x * 256 + threadIdx.x) * 4;
  if (i >= n) return;
  f32x4 v = *(const f32x4*)&s[i];
  bf16x4 o;
  #pragma unroll
  for (int j = 0; j < 4; ++j) o[j] = (__bf16)v[j];
  *(bf16x4*)&d[i] = o;
}

// ---------------- LayerNorm (wave per row) ----------------
__global__ __launch_bounds__(256) void ln_fwd(const float* __restrict__ x,
                                              const float* __restrict__ gg,
                                              const float* __restrict__ bb,
                                              __bf16* __restrict__ y) {
  const int row  = blockIdx.x * 4 + (threadIdx.x >> 6);
  const int lane = threadIdx.x & 63;
  const float* xr = x + (size_t)row * H_;
  f32x4 v[3];
  float s = 0.f, ss = 0.f;
  #pragma unroll
  for (int i = 0; i < 3; ++i) {
    v[i] = *(const f32x4*)&xr[lane * 4 + i * 256];
    #pragma unroll
    for (int j = 0; j < 4; ++j) { s += v[i][j]; ss += v[i][j] * v[i][j]; }
  }
  #pragma unroll
  for (int d = 1; d < 64; d <<= 1) { s += __shfl_xor(s, d); ss += __shfl_xor(ss, d); }
  const float mu   = s * (1.0f / 768.0f);
  const float var  = ss * (1.0f / 768.0f) - mu * mu;
  const float rstd = rsqrtf(var + 1e-6f);
  #pragma unroll
  for (int i = 0; i < 3; ++i) {
    const int c0 = lane * 4 + i * 256;
    f32x4 g4 = *(const f32x4*)&gg[c0];
    f32x4 b4 = *(const f32x4*)&bb[c0];
    bf16x4 o;
    #pragma unroll
    for (int j = 0; j < 4; ++j) o[j] = (__bf16)((v[i][j] - mu) * rstd * g4[j] + b4[j]);
    *(bf16x4*)&y[(size_t)row * H_ + c0] = o;
  }
}

// ---------------- GEMM: C[M,N] = A[M,K] * B[N,K]^T (+bias, +epilogue) ----------------
// EPI 0: bf16 out = acc + bias
// EPI 1: bf16 out = gelu_tanh(acc + bias)   (sigmoid form, no tanhf)
// EPI 2: f32  out = acc + bias + res
// 256 thr = 4 waves (2x2), tile 128x128, BK=64. LDS XOR-swizzled (slot^=(row&7))
// via pre-swizzled global source for global_load_lds (linear dest), swizzled ds_read.
template <int EPI>
__global__ __launch_bounds__(256) void gemm_bt(const __bf16* __restrict__ A,
                                               const __bf16* __restrict__ B,
                                               const float* __restrict__ bias,
                                               const float* __restrict__ res,
                                               void* __restrict__ Cv, int N, int K) {
  __shared__ __bf16 sA[128 * 64];
  __shared__ __bf16 sB[128 * 64];
  const int tid = threadIdx.x, lane = tid & 63, w = tid >> 6;
  const int lg = lane >> 4, lm = lane & 15;
  const int wr = w >> 1, wc = w & 1;
  const int m0 = blockIdx.y * 128, n0 = blockIdx.x * 128;
  const int rsub = lane >> 3;
  const int gcol = (lane & 7) ^ rsub;  // inverse-swizzled source k-slot

  const __bf16* abase = A + (size_t)(m0 + w * 32 + rsub) * K + gcol * 8;
  const __bf16* bbase = B + (size_t)(n0 + w * 32 + rsub) * K + gcol * 8;

  f32x4 acc[4][4] = {};

  const int nkt = K >> 6;
  for (int kt = 0; kt < nkt; ++kt) {
    __syncthreads();  // prior-tile reads done before overwrite
    #pragma unroll
    for (int j = 0; j < 4; ++j) {
      gll16(abase + (size_t)j * 8 * K + kt * 64, (char*)sA + (w * 4 + j) * 1024);
      gll16(bbase + (size_t)j * 8 * K + kt * 64, (char*)sB + (w * 4 + j) * 1024);
    }
    __syncthreads();  // drains vmcnt(0) before barrier

    bf16x8 af[4][2], bfr[4][2];
    #pragma unroll
    for (int f = 0; f < 4; ++f) {
      #pragma unroll
      for (int ks = 0; ks < 2; ++ks) {
        const int ra = wr * 64 + f * 16 + lm;
        const int pa = (lg + ks * 4) ^ (ra & 7);
        af[f][ks] = *(const bf16x8*)&sA[ra * 64 + pa * 8];
        const int rb = wc * 64 + f * 16 + lm;
        const int pb = (lg + ks * 4) ^ (rb & 7);
        bfr[f][ks] = *(const bf16x8*)&sB[rb * 64 + pb * 8];
      }
    }
    #pragma unroll
    for (int ks = 0; ks < 2; ++ks)
      #pragma unroll
      for (int mf = 0; mf < 4; ++mf)
        #pragma unroll
        for (int nf = 0; nf < 4; ++nf)
          acc[mf][nf] = __builtin_amdgcn_mfma_f32_16x16x32_bf16(
              af[mf][ks], bfr[nf][ks], acc[mf][nf], 0, 0, 0);
  }

  // epilogue: D layout col=lane&15, row=(lane>>4)*4+reg
  #pragma unroll
  for (int nf = 0; nf < 4; ++nf) {
    const int col = n0 + wc * 64 + nf * 16 + lm;
    const float bi = bias[col];
    #pragma unroll
    for (int mf = 0; mf < 4; ++mf) {
      #pragma unroll
      for (int q = 0; q < 4; ++q) {
        const size_t row = (size_t)(m0 + wr * 64 + mf * 16 + lg * 4 + q);
        float v = acc[mf][nf][q] + bi;
        if constexpr (EPI == 1) {
          // gelu_tanh(v) = 0.5*v*(1+tanh(u)) = v * sigmoid(2u)
          const float u = 0.7978845608028654f * (v + 0.044715f * v * v * v);
          v = v / (1.0f + __expf(-2.0f * u));
        }
        if constexpr (EPI == 2) {
          v += res[row * N + col];
          ((float*)Cv)[row * N + col] = v;
        } else {
          ((__bf16*)Cv)[row * N + col] = (__bf16)v;
        }
      }
    }
  }
}

// ---------------- V transpose: qkv[.,1536+h*64+d] -> vt[b,h,d,s] ----------------
__global__ __launch_bounds__(256) void vtrans(const __bf16* __restrict__ qkv,
                                              __bf16* __restrict__ vt) {
  __shared__ __bf16 t[64][72];
  const int b = blockIdx.z, h = blockIdx.y, st = blockIdx.x;
  const int tid = threadIdx.x;
  const int r = tid >> 2, s2 = (tid & 3) * 2;
  const __bf16* src = qkv + (size_t)(b * SEQ + st * 64 + r) * 2304 + 1536 + h * 64;
  *(bf16x8*)&t[r][s2 * 8]     = *(const bf16x8*)&src[s2 * 8];
  *(bf16x8*)&t[r][s2 * 8 + 8] = *(const bf16x8*)&src[s2 * 8 + 8];
  __syncthreads();
  __bf16* dst = vt + (size_t)((b * NH_ + h) * 64 + r) * SEQ + st * 64;
  bf16x8 a, c;
  #pragma unroll
  for (int j = 0; j < 8; ++j) { a[j] = t[s2 * 8 + j][r]; c[j] = t[s2 * 8 + 8 + j][r]; }
  *(bf16x8*)&dst[s2 * 8]     = a;
  *(bf16x8*)&dst[s2 * 8 + 8] = c;
}

// ---------------- flash attention fwd ----------------
// grid (S/128, NH, B), 256 thr = 4 waves, wave owns 32 q-rows; KV tiles of 64.
__global__ __launch_bounds__(256) void attn_fwd(const __bf16* __restrict__ qkv,
                                                const __bf16* __restrict__ vt,
                                                __bf16* __restrict__ o) {
  __shared__ __bf16 sK[64 * 64];
  __shared__ __bf16 sV[64 * 64];
  __shared__ __bf16 sP[4][32 * 64];
  const int b = blockIdx.z, h = blockIdx.y, qt = blockIdx.x;
  const int tid = threadIdx.x, lane = tid & 63, w = tid >> 6;
  const int lg = lane >> 4, lm = lane & 15;
  const size_t rowbase = (size_t)b * SEQ + qt * 128 + w * 32;

  // Q fragments (A-operand), pre-scaled by 1/8 = HD^-0.5 (exact in bf16)
  bf16x8 qf[2][2];
  #pragma unroll
  for (int mf = 0; mf < 2; ++mf)
    #pragma unroll
    for (int ks = 0; ks < 2; ++ks) {
      const __bf16* src = qkv + (rowbase + mf * 16 + lm) * 2304 + h * 64 + lg * 8 + ks * 32;
      bf16x8 t = *(const bf16x8*)src;
      #pragma unroll
      for (int j = 0; j < 8; ++j) t[j] = (__bf16)((float)t[j] * 0.125f);
      qf[mf][ks] = t;
    }

  float mreg[2][4], lreg[2][4];
  f32x4 oacc[2][4] = {};
  #pragma unroll
  for (int mf = 0; mf < 2; ++mf)
    #pragma unroll
    for (int q = 0; q < 4; ++q) { mreg[mf][q] = -3.0e38f; lreg[mf][q] = 0.f; }

  const int rsub = lane >> 3;
  const int gcol = (lane & 7) ^ rsub;
  const __bf16* kbase = qkv + (size_t)b * SEQ * 2304 + 768 + h * 64 + gcol * 8;
  const __bf16* vbase = vt + (size_t)((b * NH_ + h) * 64) * SEQ + gcol * 8;

  for (int kt = 0; kt < 16; ++kt) {
    __syncthreads();
    #pragma unroll
    for (int i = 0; i < 2; ++i) {
      const int r = (w * 2 + i) * 8 + rsub;
      gll16(kbase + (size_t)(kt * 64 + r) * 2304, (char*)sK + (w * 2 + i) * 1024);
      gll16(vbase + (size_t)r * SEQ + kt * 64,    (char*)sV + (w * 2 + i) * 1024);
    }
    __syncthreads();

    // S = Q K^T
    f32x4 sc[2][4] = {};
    bf16x8 kf[4][2];
    #pragma unroll
    for (int nf = 0; nf < 4; ++nf)
      #pragma unroll
      for (int ks = 0; ks < 2; ++ks) {
        const int row = nf * 16 + lm;
        const int ph  = (lg + ks * 4) ^ (row & 7);
        kf[nf][ks] = *(const bf16x8*)&sK[row * 64 + ph * 8];
      }
    #pragma unroll
    for (int ks = 0; ks < 2; ++ks)
      #pragma unroll
      for (int mf = 0; mf < 2; ++mf)
        #pragma unroll
        for (int nf = 0; nf < 4; ++nf)
          sc[mf][nf] = __builtin_amdgcn_mfma_f32_16x16x32_bf16(
              qf[mf][ks], kf[nf][ks], sc[mf][nf], 0, 0, 0);

    // online softmax (rows = lg*4+q+16*mf, cols across lm)
    #pragma unroll
    for (int mf = 0; mf < 2; ++mf) {
      #pragma unroll
      for (int q = 0; q < 4; ++q) {
        float tm = fmaxf(fmaxf(sc[mf][0][q], sc[mf][1][q]),
                         fmaxf(sc[mf][2][q], sc[mf][3][q]));
        tm = fmaxf(tm, __shfl_xor(tm, 1));
        tm = fmaxf(tm, __shfl_xor(tm, 2));
        tm = fmaxf(tm, __shfl_xor(tm, 4));
        tm = fmaxf(tm, __shfl_xor(tm, 8));
        const float mo = mreg[mf][q];
        const float mn = fmaxf(mo, tm);
        const float f  = __expf(mo - mn);
        mreg[mf][q] = mn;
        float rs = 0.f;
        #pragma unroll
        for (int nf = 0; nf < 4; ++nf) {
          const float p = __expf(sc[mf][nf][q] - mn);
          sc[mf][nf][q] = p;
          rs += p;
        }
        rs += __shfl_xor(rs, 1); rs += __shfl_xor(rs, 2);
        rs += __shfl_xor(rs, 4); rs += __shfl_xor(rs, 8);
        lreg[mf][q] = lreg[mf][q] * f + rs;
        #pragma unroll
        for (int nd = 0; nd < 4; ++nd) oacc[mf][nd][q] *= f;
      }
    }

    // P -> wave-private swizzled LDS
    __bf16* pw = sP[w];
    #pragma unroll
    for (int mf = 0; mf < 2; ++mf)
      #pragma unroll
      for (int nf = 0; nf < 4; ++nf)
        #pragma unroll
        for (int q = 0; q < 4; ++q) {
          const int row = mf * 16 + lg * 4 + q;
          const int col = nf * 16 + lm;
          const int ph  = (col >> 3) ^ (row & 7);
          pw[row * 64 + ph * 8 + (col & 7)] = (__bf16)sc[mf][nf][q];
        }
    asm volatile("s_waitcnt lgkmcnt(0)" ::: "memory");

    // O += P V  (A = P rows, B = Vt rows = dims)
    bf16x8 pf[2][2], vf[4][2];
    #pragma unroll
    for (int mf = 0; mf < 2; ++mf)
      #pragma unroll
      for (int ks = 0; ks < 2; ++ks) {
        const int row = mf * 16 + lm;
        const int ph  = (lg + ks * 4) ^ (row & 7);
        pf[mf][ks] = *(const bf16x8*)&pw[row * 64 + ph * 8];
      }
    #pragma unroll
    for (int nf = 0; nf < 4; ++nf)
      #pragma unroll
      for (int ks = 0; ks < 2; ++ks) {
        const int d  = nf * 16 + lm;
        const int ph = (lg + ks * 4) ^ (d & 7);
        vf[nf][ks] = *(const bf16x8*)&sV[d * 64 + ph * 8];
      }
    #pragma unroll
    for (int ks = 0; ks < 2; ++ks)
      #pragma unroll
      for (int mf = 0; mf < 2; ++mf)
        #pragma unroll
        for (int nf = 0; nf < 4; ++nf)
          oacc[mf][nf] = __builtin_amdgcn_mfma_f32_16x16x32_bf16(
              pf[mf][ks], vf[nf][ks], oacc[mf][nf], 0, 0, 0);
  }

  // epilogue: O /= l, write bf16 [NTOK, H] (cols head-major)
  #pragma unroll
  for (int mf = 0; mf < 2; ++mf) {
    #pragma unroll
    for (int q = 0; q < 4; ++q) {
      const float inv = 1.0f / lreg[mf][q];
      const size_t row = rowbase + mf * 16 + lg * 4 + q;
      #pragma unroll
      for (int nf = 0; nf < 4; ++nf) {
        const int col = h * 64 + nf * 16 + lm;
        o[row * H_ + col] = (__bf16)(oacc[mf][nf][q] * inv);
      }
    }
  }
}

// ---------------- launch ----------------
extern "C" void kernel_launch(void* const* d_in, const int* in_sizes, int n_in,
                              void* d_out, int out_size, void* d_ws, size_t ws_size,
                              hipStream_t stream) {
  const float* hs   = (const float*)d_in[0];
  const float* wq   = (const float*)d_in[1];
  const float* bq   = (const float*)d_in[2];
  const float* wk   = (const float*)d_in[3];
  const float* bk   = (const float*)d_in[4];
  const float* wv   = (const float*)d_in[5];
  const float* bv   = (const float*)d_in[6];
  const float* wo   = (const float*)d_in[7];
  const float* bo   = (const float*)d_in[8];
  const float* ln1g = (const float*)d_in[9];
  const float* ln1b = (const float*)d_in[10];
  const float* ln2g = (const float*)d_in[11];
  const float* ln2b = (const float*)d_in[12];
  const float* w1   = (const float*)d_in[13];
  const float* b1   = (const float*)d_in[14];
  const float* w2   = (const float*)d_in[15];
  const float* b2   = (const float*)d_in[16];

  // workspace layout (total 139,994,112 B ~= 133.5 MB):
  char* ws = (char*)d_ws;
  __bf16* wqkv = (__bf16*)(ws);                  //  2304*768 bf16
  __bf16* wo_b = (__bf16*)(ws + 3538944);        //   768*768
  __bf16* w1_b = (__bf16*)(ws + 4718592);        //  3072*768
  __bf16* w2_b = (__bf16*)(ws + 9437184);        //   768*3072
  float*  bqkv = (float*) (ws + 14155776);       //  2304 f32
  __bf16* xn   = (__bf16*)(ws + 14164992);       // 16384*768 (LN1 out -> attn out 'ob' -> LN2 out; lifetimes disjoint)
  __bf16* ob   = xn;                             //   alias: attn out (xn dead after QKV gemm, rewritten by LN2 later)
  __bf16* qkv  = (__bf16*)(ws + 39330816);       // 16384*2304
  __bf16* vt   = (__bf16*)(ws + 114828288);      // 16*12*64*1024
  __bf16* gb   = (__bf16*)(ws + 39330816);       // 16384*3072 (overlays qkv+vt, both dead by then)
  float*  x2   = (float*)d_out;                  // residual2 lives in d_out

  hipMemcpyAsync(bqkv,        bq, 768 * sizeof(float), hipMemcpyDeviceToDevice, stream);
  hipMemcpyAsync(bqkv + 768,  bk, 768 * sizeof(float), hipMemcpyDeviceToDevice, stream);
  hipMemcpyAsync(bqkv + 1536, bv, 768 * sizeof(float), hipMemcpyDeviceToDevice, stream);

  f2b<<<576, 256, 0, stream>>>(wq, wqkv,            589824);
  f2b<<<576, 256, 0, stream>>>(wk, wqkv + 589824,   589824);
  f2b<<<576, 256, 0, stream>>>(wv, wqkv + 1179648,  589824);
  f2b<<<576, 256, 0, stream>>>(wo, wo_b,            589824);
  f2b<<<2304, 256, 0, stream>>>(w1, w1_b,           2359296);
  f2b<<<2304, 256, 0, stream>>>(w2, w2_b,           2359296);

  ln_fwd<<<4096, 256, 0, stream>>>(hs, ln1g, ln1b, xn);
  gemm_bt<0><<<dim3(18, 128), 256, 0, stream>>>(xn, wqkv, bqkv, nullptr, qkv, 2304, 768);
  vtrans<<<dim3(16, 12, 16), 256, 0, stream>>>(qkv, vt);
  attn_fwd<<<dim3(8, 12, 16), 256, 0, stream>>>(qkv, vt, ob);
  gemm_bt<2><<<dim3(6, 128), 256, 0, stream>>>(ob, wo_b, bo, hs, (void*)x2, 768, 768);
  ln_fwd<<<4096, 256, 0, stream>>>(x2, ln2g, ln2b, xn);
  gemm_bt<1><<<dim3(24, 128), 256, 0, stream>>>(xn, w1_b, b1, nullptr, gb, 3072, 768);
  gemm_bt<2><<<dim3(6, 128), 256, 0, stream>>>(gb, w2_b, b2, x2, (void*)d_out, 768, 3072);
}

// Round 8
// 667.357 us; speedup vs baseline: 1.0494x; 1.0494x over previous
//
#include <hip/hip_runtime.h>
#include <hip/hip_bf16.h>

// VisionEncoderLayer: B=16 S=1024 H=768 NH=12 HD=64 I=3072, fp32 in/out.
// bf16 MFMA GEMMs + swapped-operand flash attention (S^T = K·Q^T so softmax
// is lane-local per q-column and P^T feeds 16x16x16 PV MFMA straight from regs).

#define H_ 768
#define I_ 3072
#define NTOK 16384   // 16*1024
#define SEQ 1024
#define NH_ 12

typedef __attribute__((ext_vector_type(8))) __bf16 bf16x8;
typedef __attribute__((ext_vector_type(4))) __bf16 bf16x4;
typedef __attribute__((ext_vector_type(4))) float  f32x4;
typedef __attribute__((ext_vector_type(4))) short  s16x4;

__device__ __forceinline__ void gll16(const void* g, void* l) {
  // async global->LDS, 16B per lane; LDS dest = wave-uniform base + lane*16
  __builtin_amdgcn_global_load_lds(
      (const __attribute__((address_space(1))) unsigned int*)g,
      (__attribute__((address_space(3))) unsigned int*)l, 16, 0, 0);
}

// PV matrix op: D = A*B + C with 16x16x16 bf16 MFMA (A,B = 2 VGPRs each).
__device__ __forceinline__ f32x4 mfma16x16x16bf16(s16x4 a, s16x4 b, f32x4 c) {
#if __has_builtin(__builtin_amdgcn_mfma_f32_16x16x16bf16_1k)
  return __builtin_amdgcn_mfma_f32_16x16x16bf16_1k(a, b, c, 0, 0, 0);
#else
  asm volatile("v_mfma_f32_16x16x16_bf16 %0, %1, %2, %0"
               : "+v"(c) : "v"(a), "v"(b));
  return c;
#endif
}

// ---------------- fp32 -> bf16 convert ----------------
__global__ __launch_bounds__(256) void f2b(const float* __restrict__ s,
                                           __bf16* __restrict__ d, int n) {
  int i = (blockIdx.x * 256 + threadIdx.x) * 4;
  if (i >= n) return;
  f32x4 v = *(const f32x4*)&s[i];
  bf16x4 o;
  #pragma unroll
  for (int j = 0; j < 4; ++j) o[j] = (__bf16)v[j];
  *(bf16x4*)&d[i] = o;
}

// ---------------- LayerNorm (wave per row) ----------------
__global__ __launch_bounds__(256) void ln_fwd(const float* __restrict__ x,
                                              const float* __restrict__ gg,
                                              const float* __restrict__ bb,
                                              __bf16* __restrict__ y) {
  const int row  = blockIdx.x * 4 + (threadIdx.x >> 6);
  const int lane = threadIdx.x & 63;
  const float* xr = x + (size_t)row * H_;
  f32x4 v[3];
  float s = 0.f, ss = 0.f;
  #pragma unroll
  for (int i = 0; i < 3; ++i) {
    v[i] = *(const f32x4*)&xr[lane * 4 + i * 256];
    #pragma unroll
    for (int j = 0; j < 4; ++j) { s += v[i][j]; ss += v[i][j] * v[i][j]; }
  }
  #pragma unroll
  for (int d = 1; d < 64; d <<= 1) { s += __shfl_xor(s, d); ss += __shfl_xor(ss, d); }
  const float mu   = s * (1.0f / 768.0f);
  const float var  = ss * (1.0f / 768.0f) - mu * mu;
  const float rstd = rsqrtf(var + 1e-6f);
  #pragma unroll
  for (int i = 0; i < 3; ++i) {
    const int c0 = lane * 4 + i * 256;
    f32x4 g4 = *(const f32x4*)&gg[c0];
    f32x4 b4 = *(const f32x4*)&bb[c0];
    bf16x4 o;
    #pragma unroll
    for (int j = 0; j < 4; ++j) o[j] = (__bf16)((v[i][j] - mu) * rstd * g4[j] + b4[j]);
    *(bf16x4*)&y[(size_t)row * H_ + c0] = o;
  }
}

// ---------------- GEMM: C[M,N] = A[M,K] * B[N,K]^T (+bias, +epilogue) ----------------
// EPI 0: bf16 out = acc + bias
// EPI 1: bf16 out = gelu_tanh(acc + bias)   (sigmoid form)
// EPI 2: f32  out = acc + bias + res
template <int EPI>
__global__ __launch_bounds__(256) void gemm_bt(const __bf16* __restrict__ A,
                                               const __bf16* __restrict__ B,
                                               const float* __restrict__ bias,
                                               const float* __restrict__ res,
                                               void* __restrict__ Cv, int N, int K) {
  __shared__ __bf16 sA[128 * 64];
  __shared__ __bf16 sB[128 * 64];
  const int tid = threadIdx.x, lane = tid & 63, w = tid >> 6;
  const int lg = lane >> 4, lm = lane & 15;
  const int wr = w >> 1, wc = w & 1;
  const int m0 = blockIdx.y * 128, n0 = blockIdx.x * 128;
  const int rsub = lane >> 3;
  const int gcol = (lane & 7) ^ rsub;  // inverse-swizzled source k-slot

  const __bf16* abase = A + (size_t)(m0 + w * 32 + rsub) * K + gcol * 8;
  const __bf16* bbase = B + (size_t)(n0 + w * 32 + rsub) * K + gcol * 8;

  f32x4 acc[4][4] = {};

  const int nkt = K >> 6;
  for (int kt = 0; kt < nkt; ++kt) {
    __syncthreads();
    #pragma unroll
    for (int j = 0; j < 4; ++j) {
      gll16(abase + (size_t)j * 8 * K + kt * 64, (char*)sA + (w * 4 + j) * 1024);
      gll16(bbase + (size_t)j * 8 * K + kt * 64, (char*)sB + (w * 4 + j) * 1024);
    }
    __syncthreads();

    bf16x8 af[4][2], bfr[4][2];
    #pragma unroll
    for (int f = 0; f < 4; ++f) {
      #pragma unroll
      for (int ks = 0; ks < 2; ++ks) {
        const int ra = wr * 64 + f * 16 + lm;
        const int pa = (lg + ks * 4) ^ (ra & 7);
        af[f][ks] = *(const bf16x8*)&sA[ra * 64 + pa * 8];
        const int rb = wc * 64 + f * 16 + lm;
        const int pb = (lg + ks * 4) ^ (rb & 7);
        bfr[f][ks] = *(const bf16x8*)&sB[rb * 64 + pb * 8];
      }
    }
    #pragma unroll
    for (int ks = 0; ks < 2; ++ks)
      #pragma unroll
      for (int mf = 0; mf < 4; ++mf)
        #pragma unroll
        for (int nf = 0; nf < 4; ++nf)
          acc[mf][nf] = __builtin_amdgcn_mfma_f32_16x16x32_bf16(
              af[mf][ks], bfr[nf][ks], acc[mf][nf], 0, 0, 0);
  }

  #pragma unroll
  for (int nf = 0; nf < 4; ++nf) {
    const int col = n0 + wc * 64 + nf * 16 + lm;
    const float bi = bias[col];
    #pragma unroll
    for (int mf = 0; mf < 4; ++mf) {
      #pragma unroll
      for (int q = 0; q < 4; ++q) {
        const size_t row = (size_t)(m0 + wr * 64 + mf * 16 + lg * 4 + q);
        float v = acc[mf][nf][q] + bi;
        if constexpr (EPI == 1) {
          const float u = 0.7978845608028654f * (v + 0.044715f * v * v * v);
          v = v / (1.0f + __expf(-2.0f * u));
        }
        if constexpr (EPI == 2) {
          v += res[row * N + col];
          ((float*)Cv)[row * N + col] = v;
        } else {
          ((__bf16*)Cv)[row * N + col] = (__bf16)v;
        }
      }
    }
  }
}

// ---------------- V transpose: qkv[.,1536+h*64+d] -> vt[b,h,d,s] ----------------
__global__ __launch_bounds__(256) void vtrans(const __bf16* __restrict__ qkv,
                                              __bf16* __restrict__ vt) {
  __shared__ __bf16 t[64][72];
  const int b = blockIdx.z, h = blockIdx.y, st = blockIdx.x;
  const int tid = threadIdx.x;
  const int r = tid >> 2, s2 = (tid & 3) * 2;
  const __bf16* src = qkv + (size_t)(b * SEQ + st * 64 + r) * 2304 + 1536 + h * 64;
  *(bf16x8*)&t[r][s2 * 8]     = *(const bf16x8*)&src[s2 * 8];
  *(bf16x8*)&t[r][s2 * 8 + 8] = *(const bf16x8*)&src[s2 * 8 + 8];
  __syncthreads();
  __bf16* dst = vt + (size_t)((b * NH_ + h) * 64 + r) * SEQ + st * 64;
  bf16x8 a, c;
  #pragma unroll
  for (int j = 0; j < 8; ++j) { a[j] = t[s2 * 8 + j][r]; c[j] = t[s2 * 8 + 8 + j][r]; }
  *(bf16x8*)&dst[s2 * 8]     = a;
  *(bf16x8*)&dst[s2 * 8 + 8] = c;
}

// ---------------- flash attention fwd (swapped operands) ----------------
// 1D grid 1536 = 8 XCD chunks x 192; q-tiles of one (b,h) stay on one XCD.
// Per wave: 32 q rows. S^T = mfma32(K,Q): lane holds col q=qblk*16+lm,
// kv rows = kvblk*16+lg*4+reg  ->  softmax reduce = 2 shfl_xor (16,32).
// P^T stays in regs: 16x16x16 PV B-frag k-index = lg*4+j matches exactly.
__global__ __launch_bounds__(256) void attn_fwd(const __bf16* __restrict__ qkv,
                                                const __bf16* __restrict__ vt,
                                                __bf16* __restrict__ o) {
  __shared__ __bf16 sK[64 * 64];
  __shared__ __bf16 sV[64 * 64];
  const int lin = blockIdx.x;
  const int xcd = lin & 7, slot = lin >> 3;
  const int workid = xcd * 192 + slot;      // bijective: 1536 = 8*192
  const int qt = workid & 7;
  const int bh = workid >> 3;
  const int b = bh / NH_, h = bh % NH_;
  const int tid = threadIdx.x, lane = tid & 63, w = tid >> 6;
  const int lg = lane >> 4, lm = lane & 15;
  const size_t rowbase = (size_t)b * SEQ + qt * 128 + w * 32;

  // Q as B-operand: col=q=qblk*16+lm, k = ks*32 + lg*8 + j; pre-scaled 1/8
  bf16x8 qf[2][2];
  #pragma unroll
  for (int qb = 0; qb < 2; ++qb)
    #pragma unroll
    for (int ks = 0; ks < 2; ++ks) {
      const __bf16* src = qkv + (rowbase + qb * 16 + lm) * 2304 + h * 64 + ks * 32 + lg * 8;
      bf16x8 t = *(const bf16x8*)src;
      #pragma unroll
      for (int j = 0; j < 8; ++j) t[j] = (__bf16)((float)t[j] * 0.125f);
      qf[qb][ks] = t;
    }

  float mreg[2] = {-3.0e38f, -3.0e38f};
  float lreg[2] = {0.f, 0.f};
  f32x4 oacc[4][2] = {};   // [dblk][qblk]: col=q, row=d=dblk*16+lg*4+reg

  const int rsub = lane >> 3;
  const int gcol = (lane & 7) ^ rsub;   // inverse swizzle on global source
  const __bf16* kbase = qkv + (size_t)b * SEQ * 2304 + 768 + h * 64 + gcol * 8;
  const __bf16* vbase = vt + (size_t)((b * NH_ + h) * 64) * SEQ + gcol * 8;

  for (int kt = 0; kt < 16; ++kt) {
    __syncthreads();
    #pragma unroll
    for (int i = 0; i < 2; ++i) {
      const int r = (w * 2 + i) * 8 + rsub;
      gll16(kbase + (size_t)(kt * 64 + r) * 2304, (char*)sK + (w * 2 + i) * 1024);
      gll16(vbase + (size_t)r * SEQ + kt * 64,    (char*)sV + (w * 2 + i) * 1024);
    }
    __syncthreads();

    // S^T = K Q^T: A=K rows(kv), B=Q cols(q)
    bf16x8 kf[4][2];
    #pragma unroll
    for (int kb = 0; kb < 4; ++kb)
      #pragma unroll
      for (int ks = 0; ks < 2; ++ks) {
        const int row = kb * 16 + lm;
        const int ph  = (lg + ks * 4) ^ (row & 7);
        kf[kb][ks] = *(const bf16x8*)&sK[row * 64 + ph * 8];
      }
    f32x4 sc[4][2] = {};
    #pragma unroll
    for (int ks = 0; ks < 2; ++ks)
      #pragma unroll
      for (int kb = 0; kb < 4; ++kb)
        #pragma unroll
        for (int qb = 0; qb < 2; ++qb)
          sc[kb][qb] = __builtin_amdgcn_mfma_f32_16x16x32_bf16(
              kf[kb][ks], qf[qb][ks], sc[kb][qb], 0, 0, 0);

    // online softmax: lane owns q col; kv spread over 16 regs x 4 lg-groups
    #pragma unroll
    for (int qb = 0; qb < 2; ++qb) {
      float t0 = fmaxf(fmaxf(sc[0][qb][0], sc[0][qb][1]), fmaxf(sc[0][qb][2], sc[0][qb][3]));
      float t1 = fmaxf(fmaxf(sc[1][qb][0], sc[1][qb][1]), fmaxf(sc[1][qb][2], sc[1][qb][3]));
      float t2 = fmaxf(fmaxf(sc[2][qb][0], sc[2][qb][1]), fmaxf(sc[2][qb][2], sc[2][qb][3]));
      float t3 = fmaxf(fmaxf(sc[3][qb][0], sc[3][qb][1]), fmaxf(sc[3][qb][2], sc[3][qb][3]));
      float tm = fmaxf(fmaxf(t0, t1), fmaxf(t2, t3));
      tm = fmaxf(tm, __shfl_xor(tm, 16));
      tm = fmaxf(tm, __shfl_xor(tm, 32));
      const float mo = mreg[qb];
      const float mn = fmaxf(mo, tm);
      const float f  = __expf(mo - mn);
      mreg[qb] = mn;
      float rs = 0.f;
      #pragma unroll
      for (int kb = 0; kb < 4; ++kb)
        #pragma unroll
        for (int r = 0; r < 4; ++r) {
          const float p = __expf(sc[kb][qb][r] - mn);
          sc[kb][qb][r] = p;
          rs += p;
        }
      rs += __shfl_xor(rs, 16);
      rs += __shfl_xor(rs, 32);
      lreg[qb] = lreg[qb] * f + rs;
      #pragma unroll
      for (int db = 0; db < 4; ++db)
        #pragma unroll
        for (int r = 0; r < 4; ++r) oacc[db][qb][r] *= f;
    }

    // P^T -> bf16 B-frags in registers (no LDS round trip)
    s16x4 pb[4][2];
    #pragma unroll
    for (int kb = 0; kb < 4; ++kb)
      #pragma unroll
      for (int qb = 0; qb < 2; ++qb) {
        union { bf16x4 h; s16x4 s; } u;
        #pragma unroll
        for (int r = 0; r < 4; ++r) u.h[r] = (__bf16)sc[kb][qb][r];
        pb[kb][qb] = u.s;
      }

    // O^T += V^T P^T via 16x16x16 MFMA (k = kv, 16 per call)
    #pragma unroll
    for (int kb = 0; kb < 4; ++kb) {
      const int kv0 = kb * 16 + lg * 4;
      const int sl  = kv0 >> 3;            // logical 8-elem slot
      const int off = kv0 & 7;             // 0 or 4
      #pragma unroll
      for (int db = 0; db < 4; ++db) {
        const int d = db * 16 + lm;
        const s16x4 va = *(const s16x4*)&sV[d * 64 + (sl ^ (d & 7)) * 8 + off];
        #pragma unroll
        for (int qb = 0; qb < 2; ++qb)
          oacc[db][qb] = mfma16x16x16bf16(va, pb[kb][qb], oacc[db][qb]);
      }
    }
  }

  // epilogue: O^T regs hold col=q, rows=4 consecutive d -> 8B stores
  #pragma unroll
  for (int qb = 0; qb < 2; ++qb) {
    const float inv = 1.0f / lreg[qb];
    const size_t row = rowbase + qb * 16 + lm;
    #pragma unroll
    for (int db = 0; db < 4; ++db) {
      bf16x4 ov;
      #pragma unroll
      for (int r = 0; r < 4; ++r) ov[r] = (__bf16)(oacc[db][qb][r] * inv);
      *(bf16x4*)&o[row * H_ + h * 64 + db * 16 + lg * 4] = ov;
    }
  }
}

// ---------------- launch ----------------
extern "C" void kernel_launch(void* const* d_in, const int* in_sizes, int n_in,
                              void* d_out, int out_size, void* d_ws, size_t ws_size,
                              hipStream_t stream) {
  const float* hs   = (const float*)d_in[0];
  const float* wq   = (const float*)d_in[1];
  const float* bq   = (const float*)d_in[2];
  const float* wk   = (const float*)d_in[3];
  const float* bk   = (const float*)d_in[4];
  const float* wv   = (const float*)d_in[5];
  const float* bv   = (const float*)d_in[6];
  const float* wo   = (const float*)d_in[7];
  const float* bo   = (const float*)d_in[8];
  const float* ln1g = (const float*)d_in[9];
  const float* ln1b = (const float*)d_in[10];
  const float* ln2g = (const float*)d_in[11];
  const float* ln2b = (const float*)d_in[12];
  const float* w1   = (const float*)d_in[13];
  const float* b1   = (const float*)d_in[14];
  const float* w2   = (const float*)d_in[15];
  const float* b2   = (const float*)d_in[16];

  char* ws = (char*)d_ws;
  __bf16* wqkv = (__bf16*)(ws);                  //  2304*768 bf16
  __bf16* wo_b = (__bf16*)(ws + 3538944);        //   768*768
  __bf16* w1_b = (__bf16*)(ws + 4718592);        //  3072*768
  __bf16* w2_b = (__bf16*)(ws + 9437184);        //   768*3072
  float*  bqkv = (float*) (ws + 14155776);       //  2304 f32
  __bf16* xn   = (__bf16*)(ws + 14164992);       // 16384*768 (LN1 out / attn out / LN2 out; disjoint lifetimes)
  __bf16* ob   = xn;
  __bf16* qkv  = (__bf16*)(ws + 39330816);       // 16384*2304
  __bf16* vt   = (__bf16*)(ws + 114828288);      // 16*12*64*1024
  __bf16* gb   = (__bf16*)(ws + 39330816);       // 16384*3072 (overlays qkv+vt, dead by then)
  float*  x2   = (float*)d_out;                  // residual2 in d_out

  hipMemcpyAsync(bqkv,        bq, 768 * sizeof(float), hipMemcpyDeviceToDevice, stream);
  hipMemcpyAsync(bqkv + 768,  bk, 768 * sizeof(float), hipMemcpyDeviceToDevice, stream);
  hipMemcpyAsync(bqkv + 1536, bv, 768 * sizeof(float), hipMemcpyDeviceToDevice, stream);

  f2b<<<576, 256, 0, stream>>>(wq, wqkv,            589824);
  f2b<<<576, 256, 0, stream>>>(wk, wqkv + 589824,   589824);
  f2b<<<576, 256, 0, stream>>>(wv, wqkv + 1179648,  589824);
  f2b<<<576, 256, 0, stream>>>(wo, wo_b,            589824);
  f2b<<<2304, 256, 0, stream>>>(w1, w1_b,           2359296);
  f2b<<<2304, 256, 0, stream>>>(w2, w2_b,           2359296);

  ln_fwd<<<4096, 256, 0, stream>>>(hs, ln1g, ln1b, xn);
  gemm_bt<0><<<dim3(18, 128), 256, 0, stream>>>(xn, wqkv, bqkv, nullptr, qkv, 2304, 768);
  vtrans<<<dim3(16, 12, 16), 256, 0, stream>>>(qkv, vt);
  attn_fwd<<<1536, 256, 0, stream>>>(qkv, vt, ob);
  gemm_bt<2><<<dim3(6, 128), 256, 0, stream>>>(ob, wo_b, bo, hs, (void*)x2, 768, 768);
  ln_fwd<<<4096, 256, 0, stream>>>(x2, ln2g, ln2b, xn);
  gemm_bt<1><<<dim3(24, 128), 256, 0, stream>>>(xn, w1_b, b1, nullptr, gb, 3072, 768);
  gemm_bt<2><<<dim3(6, 128), 256, 0, stream>>>(gb, w2_b, b2, x2, (void*)d_out, 768, 3072);
}

// Round 10
// 644.860 us; speedup vs baseline: 1.0860x; 1.0349x over previous
//
#include <hip/hip_runtime.h>
#include <hip/hip_bf16.h>

// VisionEncoderLayer: B=16 S=1024 H=768 NH=12 HD=64 I=3072, fp32 in/out.
// bf16 MFMA GEMMs (XCD-swizzled 1D grid) + swapped-operand flash attention.

#define H_ 768
#define I_ 3072
#define NTOK 16384   // 16*1024
#define SEQ 1024
#define NH_ 12

typedef __attribute__((ext_vector_type(8))) __bf16 bf16x8;
typedef __attribute__((ext_vector_type(4))) __bf16 bf16x4;
typedef __attribute__((ext_vector_type(4))) float  f32x4;
typedef __attribute__((ext_vector_type(4))) short  s16x4;

__device__ __forceinline__ void gll16(const void* g, void* l) {
  // async global->LDS, 16B per lane; LDS dest = wave-uniform base + lane*16
  __builtin_amdgcn_global_load_lds(
      (const __attribute__((address_space(1))) unsigned int*)g,
      (__attribute__((address_space(3))) unsigned int*)l, 16, 0, 0);
}

// PV matrix op: D = A*B + C with 16x16x16 bf16 MFMA (A,B = 2 VGPRs each).
__device__ __forceinline__ f32x4 mfma16x16x16bf16(s16x4 a, s16x4 b, f32x4 c) {
#if __has_builtin(__builtin_amdgcn_mfma_f32_16x16x16bf16_1k)
  return __builtin_amdgcn_mfma_f32_16x16x16bf16_1k(a, b, c, 0, 0, 0);
#else
  asm volatile("v_mfma_f32_16x16x16_bf16 %0, %1, %2, %0"
               : "+v"(c) : "v"(a), "v"(b));
  return c;
#endif
}

// ---------------- fp32 -> bf16 convert ----------------
__global__ __launch_bounds__(256) void f2b(const float* __restrict__ s,
                                           __bf16* __restrict__ d, int n) {
  int i = (blockIdx.x * 256 + threadIdx.x) * 4;
  if (i >= n) return;
  f32x4 v = *(const f32x4*)&s[i];
  bf16x4 o;
  #pragma unroll
  for (int j = 0; j < 4; ++j) o[j] = (__bf16)v[j];
  *(bf16x4*)&d[i] = o;
}

// ---------------- LayerNorm (wave per row) ----------------
__global__ __launch_bounds__(256) void ln_fwd(const float* __restrict__ x,
                                              const float* __restrict__ gg,
                                              const float* __restrict__ bb,
                                              __bf16* __restrict__ y) {
  const int row  = blockIdx.x * 4 + (threadIdx.x >> 6);
  const int lane = threadIdx.x & 63;
  const float* xr = x + (size_t)row * H_;
  f32x4 v[3];
  float s = 0.f, ss = 0.f;
  #pragma unroll
  for (int i = 0; i < 3; ++i) {
    v[i] = *(const f32x4*)&xr[lane * 4 + i * 256];
    #pragma unroll
    for (int j = 0; j < 4; ++j) { s += v[i][j]; ss += v[i][j] * v[i][j]; }
  }
  #pragma unroll
  for (int d = 1; d < 64; d <<= 1) { s += __shfl_xor(s, d); ss += __shfl_xor(ss, d); }
  const float mu   = s * (1.0f / 768.0f);
  const float var  = ss * (1.0f / 768.0f) - mu * mu;
  const float rstd = rsqrtf(var + 1e-6f);
  #pragma unroll
  for (int i = 0; i < 3; ++i) {
    const int c0 = lane * 4 + i * 256;
    f32x4 g4 = *(const f32x4*)&gg[c0];
    f32x4 b4 = *(const f32x4*)&bb[c0];
    bf16x4 o;
    #pragma unroll
    for (int j = 0; j < 4; ++j) o[j] = (__bf16)((v[i][j] - mu) * rstd * g4[j] + b4[j]);
    *(bf16x4*)&y[(size_t)row * H_ + c0] = o;
  }
}

// ---------------- GEMM: C[M,N] = A[M,K] * B[N,K]^T (+bias, +epilogue) ----------------
// EPI 0: bf16 out = acc + bias
// EPI 1: bf16 out = gelu_tanh(acc + bias)   (sigmoid form)
// EPI 2: f32  out = acc + bias + res
// 1D grid (nwg % 8 == 0), bijective XCD swizzle: each XCD owns a contiguous
// y-range (x fastest inside) so each A-panel is fetched once chip-wide (T1).
template <int EPI>
__global__ __launch_bounds__(256) void gemm_bt(const __bf16* __restrict__ A,
                                               const __bf16* __restrict__ B,
                                               const float* __restrict__ bias,
                                               const float* __restrict__ res,
                                               void* __restrict__ Cv, int N, int K,
                                               int nx) {
  __shared__ __bf16 sA[128 * 64];
  __shared__ __bf16 sB[128 * 64];
  const int nwg = gridDim.x;
  const int cpx = nwg >> 3;                       // blocks per XCD chunk
  const int wg  = ((blockIdx.x & 7) * cpx) + (blockIdx.x >> 3);
  const int xt  = wg % nx, yt = wg / nx;
  const int m0 = yt * 128, n0 = xt * 128;

  const int tid = threadIdx.x, lane = tid & 63, w = tid >> 6;
  const int lg = lane >> 4, lm = lane & 15;
  const int wr = w >> 1, wc = w & 1;
  const int rsub = lane >> 3;
  const int gcol = (lane & 7) ^ rsub;  // inverse-swizzled source k-slot

  const __bf16* abase = A + (size_t)(m0 + w * 32 + rsub) * K + gcol * 8;
  const __bf16* bbase = B + (size_t)(n0 + w * 32 + rsub) * K + gcol * 8;

  f32x4 acc[4][4] = {};

  const int nkt = K >> 6;
  for (int kt = 0; kt < nkt; ++kt) {
    __syncthreads();
    #pragma unroll
    for (int j = 0; j < 4; ++j) {
      gll16(abase + (size_t)j * 8 * K + kt * 64, (char*)sA + (w * 4 + j) * 1024);
      gll16(bbase + (size_t)j * 8 * K + kt * 64, (char*)sB + (w * 4 + j) * 1024);
    }
    __syncthreads();

    bf16x8 af[4][2], bfr[4][2];
    #pragma unroll
    for (int f = 0; f < 4; ++f) {
      #pragma unroll
      for (int ks = 0; ks < 2; ++ks) {
        const int ra = wr * 64 + f * 16 + lm;
        const int pa = (lg + ks * 4) ^ (ra & 7);
        af[f][ks] = *(const bf16x8*)&sA[ra * 64 + pa * 8];
        const int rb = wc * 64 + f * 16 + lm;
        const int pb = (lg + ks * 4) ^ (rb & 7);
        bfr[f][ks] = *(const bf16x8*)&sB[rb * 64 + pb * 8];
      }
    }
    #pragma unroll
    for (int ks = 0; ks < 2; ++ks)
      #pragma unroll
      for (int mf = 0; mf < 4; ++mf)
        #pragma unroll
        for (int nf = 0; nf < 4; ++nf)
          acc[mf][nf] = __builtin_amdgcn_mfma_f32_16x16x32_bf16(
              af[mf][ks], bfr[nf][ks], acc[mf][nf], 0, 0, 0);
  }

  #pragma unroll
  for (int nf = 0; nf < 4; ++nf) {
    const int col = n0 + wc * 64 + nf * 16 + lm;
    const float bi = bias[col];
    #pragma unroll
    for (int mf = 0; mf < 4; ++mf) {
      #pragma unroll
      for (int q = 0; q < 4; ++q) {
        const size_t row = (size_t)(m0 + wr * 64 + mf * 16 + lg * 4 + q);
        float v = acc[mf][nf][q] + bi;
        if constexpr (EPI == 1) {
          const float u = 0.7978845608028654f * (v + 0.044715f * v * v * v);
          v = v / (1.0f + __expf(-2.0f * u));
        }
        if constexpr (EPI == 2) {
          v += res[row * N + col];
          ((float*)Cv)[row * N + col] = v;
        } else {
          ((__bf16*)Cv)[row * N + col] = (__bf16)v;
        }
      }
    }
  }
}

// ---------------- V transpose: qkv[.,1536+h*64+d] -> vt[b,h,d,s] ----------------
__global__ __launch_bounds__(256) void vtrans(const __bf16* __restrict__ qkv,
                                              __bf16* __restrict__ vt) {
  __shared__ __bf16 t[64][72];
  const int b = blockIdx.z, h = blockIdx.y, st = blockIdx.x;
  const int tid = threadIdx.x;
  const int r = tid >> 2, s2 = (tid & 3) * 2;
  const __bf16* src = qkv + (size_t)(b * SEQ + st * 64 + r) * 2304 + 1536 + h * 64;
  *(bf16x8*)&t[r][s2 * 8]     = *(const bf16x8*)&src[s2 * 8];
  *(bf16x8*)&t[r][s2 * 8 + 8] = *(const bf16x8*)&src[s2 * 8 + 8];
  __syncthreads();
  __bf16* dst = vt + (size_t)((b * NH_ + h) * 64 + r) * SEQ + st * 64;
  bf16x8 a, c;
  #pragma unroll
  for (int j = 0; j < 8; ++j) { a[j] = t[s2 * 8 + j][r]; c[j] = t[s2 * 8 + 8 + j][r]; }
  *(bf16x8*)&dst[s2 * 8]     = a;
  *(bf16x8*)&dst[s2 * 8 + 8] = c;
}

// ---------------- flash attention fwd (swapped operands) ----------------
// 1D grid 1536 = 8 XCD chunks x 192; q-tiles of one (b,h) stay on one XCD.
// Per wave: 32 q rows. S^T = mfma32(K,Q): lane holds col q=qblk*16+lm,
// kv rows = kvblk*16+lg*4+reg  ->  softmax reduce = 2 shfl_xor (16,32).
// P^T stays in regs: 16x16x16 PV B-frag k-index = lg*4+j matches exactly.
__global__ __launch_bounds__(256) void attn_fwd(const __bf16* __restrict__ qkv,
                                                const __bf16* __restrict__ vt,
                                                __bf16* __restrict__ o) {
  __shared__ __bf16 sK[64 * 64];
  __shared__ __bf16 sV[64 * 64];
  const int lin = blockIdx.x;
  const int xcd = lin & 7, slot = lin >> 3;
  const int workid = xcd * 192 + slot;      // bijective: 1536 = 8*192
  const int qt = workid & 7;
  const int bh = workid >> 3;
  const int b = bh / NH_, h = bh % NH_;
  const int tid = threadIdx.x, lane = tid & 63, w = tid >> 6;
  const int lg = lane >> 4, lm = lane & 15;
  const size_t rowbase = (size_t)b * SEQ + qt * 128 + w * 32;

  // Q as B-operand: col=q=qblk*16+lm, k = ks*32 + lg*8 + j; pre-scaled 1/8
  bf16x8 qf[2][2];
  #pragma unroll
  for (int qb = 0; qb < 2; ++qb)
    #pragma unroll
    for (int ks = 0; ks < 2; ++ks) {
      const __bf16* src = qkv + (rowbase + qb * 16 + lm) * 2304 + h * 64 + ks * 32 + lg * 8;
      bf16x8 t = *(const bf16x8*)src;
      #pragma unroll
      for (int j = 0; j < 8; ++j) t[j] = (__bf16)((float)t[j] * 0.125f);
      qf[qb][ks] = t;
    }

  float mreg[2] = {-3.0e38f, -3.0e38f};
  float lreg[2] = {0.f, 0.f};
  f32x4 oacc[4][2] = {};   // [dblk][qblk]: col=q, row=d=dblk*16+lg*4+reg

  const int rsub = lane >> 3;
  const int gcol = (lane & 7) ^ rsub;   // inverse swizzle on global source
  const __bf16* kbase = qkv + (size_t)b * SEQ * 2304 + 768 + h * 64 + gcol * 8;
  const __bf16* vbase = vt + (size_t)((b * NH_ + h) * 64) * SEQ + gcol * 8;

  for (int kt = 0; kt < 16; ++kt) {
    __syncthreads();
    #pragma unroll
    for (int i = 0; i < 2; ++i) {
      const int r = (w * 2 + i) * 8 + rsub;
      gll16(kbase + (size_t)(kt * 64 + r) * 2304, (char*)sK + (w * 2 + i) * 1024);
      gll16(vbase + (size_t)r * SEQ + kt * 64,    (char*)sV + (w * 2 + i) * 1024);
    }
    __syncthreads();

    // S^T = K Q^T: A=K rows(kv), B=Q cols(q)
    bf16x8 kf[4][2];
    #pragma unroll
    for (int kb = 0; kb < 4; ++kb)
      #pragma unroll
      for (int ks = 0; ks < 2; ++ks) {
        const int row = kb * 16 + lm;
        const int ph  = (lg + ks * 4) ^ (row & 7);
        kf[kb][ks] = *(const bf16x8*)&sK[row * 64 + ph * 8];
      }
    f32x4 sc[4][2] = {};
    #pragma unroll
    for (int ks = 0; ks < 2; ++ks)
      #pragma unroll
      for (int kb = 0; kb < 4; ++kb)
        #pragma unroll
        for (int qb = 0; qb < 2; ++qb)
          sc[kb][qb] = __builtin_amdgcn_mfma_f32_16x16x32_bf16(
              kf[kb][ks], qf[qb][ks], sc[kb][qb], 0, 0, 0);

    // online softmax: lane owns q col; kv spread over 16 regs x 4 lg-groups
    #pragma unroll
    for (int qb = 0; qb < 2; ++qb) {
      float t0 = fmaxf(fmaxf(sc[0][qb][0], sc[0][qb][1]), fmaxf(sc[0][qb][2], sc[0][qb][3]));
      float t1 = fmaxf(fmaxf(sc[1][qb][0], sc[1][qb][1]), fmaxf(sc[1][qb][2], sc[1][qb][3]));
      float t2 = fmaxf(fmaxf(sc[2][qb][0], sc[2][qb][1]), fmaxf(sc[2][qb][2], sc[2][qb][3]));
      float t3 = fmaxf(fmaxf(sc[3][qb][0], sc[3][qb][1]), fmaxf(sc[3][qb][2], sc[3][qb][3]));
      float tm = fmaxf(fmaxf(t0, t1), fmaxf(t2, t3));
      tm = fmaxf(tm, __shfl_xor(tm, 16));
      tm = fmaxf(tm, __shfl_xor(tm, 32));
      const float mo = mreg[qb];
      const float mn = fmaxf(mo, tm);
      const float f  = __expf(mo - mn);
      mreg[qb] = mn;
      float rs = 0.f;
      #pragma unroll
      for (int kb = 0; kb < 4; ++kb)
        #pragma unroll
        for (int r = 0; r < 4; ++r) {
          const float p = __expf(sc[kb][qb][r] - mn);
          sc[kb][qb][r] = p;
          rs += p;
        }
      rs += __shfl_xor(rs, 16);
      rs += __shfl_xor(rs, 32);
      lreg[qb] = lreg[qb] * f + rs;
      #pragma unroll
      for (int db = 0; db < 4; ++db)
        #pragma unroll
        for (int r = 0; r < 4; ++r) oacc[db][qb][r] *= f;
    }

    // P^T -> bf16 B-frags in registers (no LDS round trip)
    s16x4 pb[4][2];
    #pragma unroll
    for (int kb = 0; kb < 4; ++kb)
      #pragma unroll
      for (int qb = 0; qb < 2; ++qb) {
        union { bf16x4 h; s16x4 s; } u;
        #pragma unroll
        for (int r = 0; r < 4; ++r) u.h[r] = (__bf16)sc[kb][qb][r];
        pb[kb][qb] = u.s;
      }

    // O^T += V^T P^T via 16x16x16 MFMA (k = kv, 16 per call)
    #pragma unroll
    for (int kb = 0; kb < 4; ++kb) {
      const int kv0 = kb * 16 + lg * 4;
      const int sl  = kv0 >> 3;            // logical 8-elem slot
      const int off = kv0 & 7;             // 0 or 4
      #pragma unroll
      for (int db = 0; db < 4; ++db) {
        const int d = db * 16 + lm;
        const s16x4 va = *(const s16x4*)&sV[d * 64 + (sl ^ (d & 7)) * 8 + off];
        #pragma unroll
        for (int qb = 0; qb < 2; ++qb)
          oacc[db][qb] = mfma16x16x16bf16(va, pb[kb][qb], oacc[db][qb]);
      }
    }
  }

  // epilogue: O^T regs hold col=q, rows=4 consecutive d -> 8B stores
  #pragma unroll
  for (int qb = 0; qb < 2; ++qb) {
    const float inv = 1.0f / lreg[qb];
    const size_t row = rowbase + qb * 16 + lm;
    #pragma unroll
    for (int db = 0; db < 4; ++db) {
      bf16x4 ov;
      #pragma unroll
      for (int r = 0; r < 4; ++r) ov[r] = (__bf16)(oacc[db][qb][r] * inv);
      *(bf16x4*)&o[row * H_ + h * 64 + db * 16 + lg * 4] = ov;
    }
  }
}

// ---------------- launch ----------------
extern "C" void kernel_launch(void* const* d_in, const int* in_sizes, int n_in,
                              void* d_out, int out_size, void* d_ws, size_t ws_size,
                              hipStream_t stream) {
  const float* hs   = (const float*)d_in[0];
  const float* wq   = (const float*)d_in[1];
  const float* bq   = (const float*)d_in[2];
  const float* wk   = (const float*)d_in[3];
  const float* bk   = (const float*)d_in[4];
  const float* wv   = (const float*)d_in[5];
  const float* bv   = (const float*)d_in[6];
  const float* wo   = (const float*)d_in[7];
  const float* bo   = (const float*)d_in[8];
  const float* ln1g = (const float*)d_in[9];
  const float* ln1b = (const float*)d_in[10];
  const float* ln2g = (const float*)d_in[11];
  const float* ln2b = (const float*)d_in[12];
  const float* w1   = (const float*)d_in[13];
  const float* b1   = (const float*)d_in[14];
  const float* w2   = (const float*)d_in[15];
  const float* b2   = (const float*)d_in[16];

  char* ws = (char*)d_ws;
  __bf16* wqkv = (__bf16*)(ws);                  //  2304*768 bf16
  __bf16* wo_b = (__bf16*)(ws + 3538944);        //   768*768
  __bf16* w1_b = (__bf16*)(ws + 4718592);        //  3072*768
  __bf16* w2_b = (__bf16*)(ws + 9437184);        //   768*3072
  float*  bqkv = (float*) (ws + 14155776);       //  2304 f32
  __bf16* xn   = (__bf16*)(ws + 14164992);       // 16384*768 (LN1 out / attn out / LN2 out; disjoint lifetimes)
  __bf16* ob   = xn;
  __bf16* qkv  = (__bf16*)(ws + 39330816);       // 16384*2304
  __bf16* vt   = (__bf16*)(ws + 114828288);      // 16*12*64*1024
  __bf16* gb   = (__bf16*)(ws + 39330816);       // 16384*3072 (overlays qkv+vt, dead by then)
  float*  x2   = (float*)d_out;                  // residual2 in d_out

  hipMemcpyAsync(bqkv,        bq, 768 * sizeof(float), hipMemcpyDeviceToDevice, stream);
  hipMemcpyAsync(bqkv + 768,  bk, 768 * sizeof(float), hipMemcpyDeviceToDevice, stream);
  hipMemcpyAsync(bqkv + 1536, bv, 768 * sizeof(float), hipMemcpyDeviceToDevice, stream);

  f2b<<<576, 256, 0, stream>>>(wq, wqkv,            589824);
  f2b<<<576, 256, 0, stream>>>(wk, wqkv + 589824,   589824);
  f2b<<<576, 256, 0, stream>>>(wv, wqkv + 1179648,  589824);
  f2b<<<576, 256, 0, stream>>>(wo, wo_b,            589824);
  f2b<<<2304, 256, 0, stream>>>(w1, w1_b,           2359296);
  f2b<<<2304, 256, 0, stream>>>(w2, w2_b,           2359296);

  ln_fwd<<<4096, 256, 0, stream>>>(hs, ln1g, ln1b, xn);
  // 1D swizzled grids: nwg = nx * (M/128), all divisible by 8
  gemm_bt<0><<<2304, 256, 0, stream>>>(xn, wqkv, bqkv, nullptr, qkv, 2304, 768, 18);
  vtrans<<<dim3(16, 12, 16), 256, 0, stream>>>(qkv, vt);
  attn_fwd<<<1536, 256, 0, stream>>>(qkv, vt, ob);
  gemm_bt<2><<<768, 256, 0, stream>>>(ob, wo_b, bo, hs, (void*)x2, 768, 768, 6);
  ln_fwd<<<4096, 256, 0, stream>>>(x2, ln2g, ln2b, xn);
  gemm_bt<1><<<3072, 256, 0, stream>>>(xn, w1_b, b1, nullptr, gb, 3072, 768, 24);
  gemm_bt<2><<<768, 256, 0, stream>>>(gb, w2_b, b2, x2, (void*)d_out, 768, 3072, 6);
}